// Round 3
// baseline (15880.779 us; speedup 1.0000x reference)
//
#include <hip/hip_runtime.h>
#include <cstdint>
#include <cstddef>

#define NB 32
#define NT 64
#define NV 32000
#define NE 512
#define NH 1024
#define BOS_ID 1
#define EOS_ID 3

__device__ __forceinline__ unsigned mono_f32(float f) {
    unsigned u = __float_as_uint(f);
    return (u & 0x80000000u) ? ~u : (u | 0x80000000u);
}

// h0 = img @ Wp^T + bp ; c = 0
__global__ __launch_bounds__(256) void k_init(const float* __restrict__ img,
                                              const float* __restrict__ Wp,
                                              const float* __restrict__ bp,
                                              float* __restrict__ h0,
                                              float* __restrict__ c) {
    int g = blockIdx.x * 256 + threadIdx.x;   // 32768 outputs, one per thread
    int j = g >> 5, b = g & 31;
    const float* ir = img + (size_t)b * NH;   // D == 1024
    const float* wr = Wp + (size_t)j * NH;
    float s = bp[j];
    for (int k = 0; k < NH; k++) s = fmaf(ir[k], wr[k], s);
    h0[b * NH + j] = s;
    c[b * NH + j]  = 0.0f;
}

// logits + gumbel + argmax partial via device atomicMax.
// v4: LDS-free GEMV. 500 blocks x 256 threads (4 waves).
//   lane l <-> v = blk*64 + l (one v per lane; W row read in whole 64B lines,
//   once, directly from global -- no LDS staging, no barriers in main loop).
//   wave w <-> k-quarter [256w, 256w+256): acc[32 b] per lane.
//   h operand is wave-uniform (indexed by b,k only) -> scalarizable loads.
//   Cross-wave k-reduce via padded LDS once at end; then gumbel+argmax with
//   the same mono_f32 / ~v / atomicMax key semantics as prior rounds.
__global__ __launch_bounds__(256) void k_logit(const float* __restrict__ h,
                                               const float* __restrict__ Whv,
                                               const float* __restrict__ bhv,
                                               const float* __restrict__ gu,
                                               int s,
                                               unsigned long long* __restrict__ slot) {
    __shared__ float red[4][64][33];          // [kq][lane=v][b], pad 33: 2-way free
    const int tid = threadIdx.x;
    const int w   = tid >> 6;                 // wave = k-quarter
    const int l   = tid & 63;                 // lane = v offset
    const int v   = blockIdx.x * 64 + l;
    const float* __restrict__ wrow = Whv + (size_t)v * NH + w * 256;
    const float* __restrict__ hq   = h + w * 256;

    float acc[32];
#pragma unroll
    for (int b = 0; b < 32; b++) acc[b] = 0.f;

    for (int c = 0; c < 16; c++) {            // 16-k (64 B) segments of the quarter
        const float4 w0 = *(const float4*)&wrow[c * 16 + 0];
        const float4 w1 = *(const float4*)&wrow[c * 16 + 4];
        const float4 w2 = *(const float4*)&wrow[c * 16 + 8];
        const float4 w3 = *(const float4*)&wrow[c * 16 + 12];
#pragma unroll
        for (int b = 0; b < 32; b++) {
            const float* hb = &hq[b * NH + c * 16];
            const float4 h0 = *(const float4*)&hb[0];
            const float4 h1 = *(const float4*)&hb[4];
            const float4 h2 = *(const float4*)&hb[8];
            const float4 h3 = *(const float4*)&hb[12];
            float a = acc[b];
            a = fmaf(h0.x, w0.x, a); a = fmaf(h0.y, w0.y, a);
            a = fmaf(h0.z, w0.z, a); a = fmaf(h0.w, w0.w, a);
            a = fmaf(h1.x, w1.x, a); a = fmaf(h1.y, w1.y, a);
            a = fmaf(h1.z, w1.z, a); a = fmaf(h1.w, w1.w, a);
            a = fmaf(h2.x, w2.x, a); a = fmaf(h2.y, w2.y, a);
            a = fmaf(h2.z, w2.z, a); a = fmaf(h2.w, w2.w, a);
            a = fmaf(h3.x, w3.x, a); a = fmaf(h3.y, w3.y, a);
            a = fmaf(h3.z, w3.z, a); a = fmaf(h3.w, w3.w, a);
            acc[b] = a;
        }
    }

    // cross-wave reduce: wave w wrote its quarter-partials; each wave then
    // finalizes b in [8w, 8w+8) for all 64 v (its lanes).
#pragma unroll
    for (int b = 0; b < 32; b++) red[w][l][b] = acc[b];
    __syncthreads();

    const float bv = bhv[v];
    const size_t gubase = (size_t)s * NB * NV;
#pragma unroll
    for (int i = 0; i < 8; i++) {
        const int b = w * 8 + i;
        float f = ((red[0][l][b] + red[1][l][b]) + red[2][l][b]) + red[3][l][b];
        float u = gu[gubase + (size_t)b * NV + v];
        float g  = -logf(-logf(u + 1e-10f) + 1e-10f);
        float sc = f + bv + g;                // TAU == 1.0
        unsigned long long key =
            ((unsigned long long)mono_f32(sc) << 32) | (unsigned)(~(unsigned)v);
#pragma unroll
        for (int m = 1; m < 64; m <<= 1) {
            unsigned long long o =
                (unsigned long long)__shfl_xor((long long)key, m, 64);
            if (o > key) key = o;
        }
        if (l == 0) atomicMax(&slot[(s & 1) * 32 + b], key);
    }
}

// argmax-finalize (read slots) + LSTM cell slice (4 h-outputs per block)
// v2: T14 async-stage split -- issue next chunk's global loads into regs
// before computing the current chunk; write regs->LDS after the barrier.
// Staging indices / LDS layout / per-thread k-order identical to v1.
__global__ __launch_bounds__(256) void k_lstm(const float* __restrict__ h,
                                              float* __restrict__ hn,
                                              float* __restrict__ cbuf,
                                              const float* __restrict__ emb,
                                              const float* __restrict__ Wih,
                                              const float* __restrict__ Whh,
                                              const float* __restrict__ bih,
                                              const float* __restrict__ bhh,
                                              unsigned long long* __restrict__ slot,
                                              int* __restrict__ hist,
                                              int s, int skip) {
    __shared__ float Wt[512][20];   // [k][slot], stride 20: aligned f4, conflict-free reads
    __shared__ float xh[32][517];   // [b][k], stride 517: 2-way max on reads
    __shared__ int labels[32];
    const int tid = threadIdx.x, blk = blockIdx.x;
    const int b8 = tid >> 3, ks = tid & 7;

    if (s < 0) {
        if (tid < 32) labels[tid] = BOS_ID;
    } else {
        if (tid < 32) labels[tid] = (int)(~(unsigned)slot[(s & 1) * 32 + tid]);
    }
    if (tid >= 32 && tid < 64)
        slot[((s + 1) & 1) * 32 + (tid - 32)] = 0ull;   // pre-zero next parity
    if (s >= 0 && blk == 0 && tid < 32) hist[s * 32 + tid] = labels[tid];
    if (skip) return;

    const int j0 = blk * 4;
    float acc[16];
#pragma unroll
    for (int r = 0; r < 16; r++) acc[r] = 0.f;

    float wreg[32];
    float xreg[64];
    auto issue = [&](int chunk) {
#pragma unroll
        for (int i = 0; i < 32; i++) {     // 16 gate rows x 512 k -> regs
            int idx = i * 256 + tid;
            int slot_i = idx >> 9, k = idx & 511;
            int gate = slot_i >> 2, jj = slot_i & 3;
            int row = gate * NH + j0 + jj;
            wreg[i] = (chunk == 0) ? Wih[(size_t)row * NE + k]
                                   : Whh[(size_t)row * NH + (chunk - 1) * 512 + k];
        }
#pragma unroll
        for (int i = 0; i < 64; i++) {     // x / h chunk -> regs
            int idx = i * 256 + tid;
            int b = idx >> 9, k = idx & 511;
            xreg[i] = (chunk == 0) ? emb[(size_t)labels[b] * NE + k]
                                   : h[b * NH + (chunk - 1) * 512 + k];
        }
    };

    __syncthreads();                       // labels visible to all threads
    issue(0);
    for (int chunk = 0; chunk < 3; chunk++) {
        __syncthreads();                   // prior compute on LDS done
#pragma unroll
        for (int i = 0; i < 32; i++) {
            int idx = i * 256 + tid;
            Wt[idx & 511][idx >> 9] = wreg[i];
        }
#pragma unroll
        for (int i = 0; i < 64; i++) {
            int idx = i * 256 + tid;
            xh[idx >> 9][idx & 511] = xreg[i];
        }
        if (chunk < 2) issue(chunk + 1);   // overlap next-chunk loads w/ compute
        __syncthreads();
#pragma unroll 4
        for (int i = 0; i < 64; i++) {
            int k = ks + 8 * i;
            float xv = xh[b8][k];
            const float4 w0 = *(const float4*)&Wt[k][0];
            const float4 w1 = *(const float4*)&Wt[k][4];
            const float4 w2 = *(const float4*)&Wt[k][8];
            const float4 w3 = *(const float4*)&Wt[k][12];
            acc[0]  = fmaf(xv, w0.x, acc[0]);  acc[1]  = fmaf(xv, w0.y, acc[1]);
            acc[2]  = fmaf(xv, w0.z, acc[2]);  acc[3]  = fmaf(xv, w0.w, acc[3]);
            acc[4]  = fmaf(xv, w1.x, acc[4]);  acc[5]  = fmaf(xv, w1.y, acc[5]);
            acc[6]  = fmaf(xv, w1.z, acc[6]);  acc[7]  = fmaf(xv, w1.w, acc[7]);
            acc[8]  = fmaf(xv, w2.x, acc[8]);  acc[9]  = fmaf(xv, w2.y, acc[9]);
            acc[10] = fmaf(xv, w2.z, acc[10]); acc[11] = fmaf(xv, w2.w, acc[11]);
            acc[12] = fmaf(xv, w3.x, acc[12]); acc[13] = fmaf(xv, w3.y, acc[13]);
            acc[14] = fmaf(xv, w3.z, acc[14]); acc[15] = fmaf(xv, w3.w, acc[15]);
        }
    }
#pragma unroll
    for (int m = 1; m < 8; m <<= 1)
#pragma unroll
        for (int r = 0; r < 16; r++) acc[r] += __shfl_xor(acc[r], m, 64);

    if (ks == 0) {
        int b = b8;
#pragma unroll
        for (int jj = 0; jj < 4; jj++) {
            int j = j0 + jj;
            float gi = acc[0 + jj]  + bih[j]          + bhh[j];
            float gf = acc[4 + jj]  + bih[NH + j]     + bhh[NH + j];
            float gg = acc[8 + jj]  + bih[2 * NH + j] + bhh[2 * NH + j];
            float go = acc[12 + jj] + bih[3 * NH + j] + bhh[3 * NH + j];
            float si = 1.f / (1.f + expf(-gi));
            float sf = 1.f / (1.f + expf(-gf));
            float so = 1.f / (1.f + expf(-go));
            float cn = sf * cbuf[b * NH + j] + si * tanhf(gg);
            float hv = so * tanhf(cn);
            cbuf[b * NH + j] = cn;
            hn[b * NH + j]   = hv;
        }
    }
}

// ids / lengths from label history
__global__ __launch_bounds__(64) void k_out(const int* __restrict__ hist,
                                            float* __restrict__ out) {
    int b = threadIdx.x;
    if (b >= 32) return;
    int te = 63;   // first EOS index (t=63 forced EOS)
    for (int t = 0; t < 63; t++)
        if (hist[t * 32 + b] == EOS_ID) { te = t; break; }
    for (int t = 0; t < 64; t++) {
        int lab = (t < 63) ? hist[t * 32 + b] : EOS_ID;
        int id = (t < te) ? lab : 0;           // pad_g true strictly before first EOS
        out[b * 64 + t] = (float)id;
    }
    out[2048 + (size_t)NB * NT * NV + b] = (float)(te + 1);
}

// zero logits region + scatter one-hot (message_logits == one_hot(message_ids))
__global__ __launch_bounds__(256) void k_scatter(float* __restrict__ out) {
    const int bt = blockIdx.x;                 // b*64 + t
    float* row = out + 2048 + (size_t)bt * NV;
    const int id = (int)out[bt];               // ids already written by k_out
    float4 z = make_float4(0.f, 0.f, 0.f, 0.f);
    for (int i = threadIdx.x; i < NV / 4; i += 256) ((float4*)row)[i] = z;
    __syncthreads();
    if (threadIdx.x == 0) row[id] = 1.0f;
}

extern "C" void kernel_launch(void* const* d_in, const int* in_sizes, int n_in,
                              void* d_out, int out_size, void* d_ws, size_t ws_size,
                              hipStream_t stream) {
    const float* img = (const float*)d_in[0];
    const float* gu  = (const float*)d_in[1];
    const float* Wp  = (const float*)d_in[2];
    const float* bp  = (const float*)d_in[3];
    const float* emb = (const float*)d_in[4];
    const float* Wih = (const float*)d_in[5];
    const float* Whh = (const float*)d_in[6];
    const float* bih = (const float*)d_in[7];
    const float* bhh = (const float*)d_in[8];
    const float* Whv = (const float*)d_in[9];
    const float* bhv = (const float*)d_in[10];
    float* out = (float*)d_out;

    // scratch lives inside the logits region of d_out (fully overwritten by k_scatter)
    float* scratch = out + 2048;
    float* hA = scratch;                 // 32768
    float* hB = scratch + 32768;         // 32768
    float* cb = scratch + 65536;         // 32768
    unsigned long long* slot = (unsigned long long*)(scratch + 98304); // 64 u64 (2 parities)
    int* hist = (int*)(scratch + 98304 + 128);                         // 63*32 ints

    k_init<<<128, 256, 0, stream>>>(img, Wp, bp, hB, cb);
    // initial LSTM cell with x0 = emb[BOS], h = h0, c = 0 -> writes hA; zeroes slot parity 0
    k_lstm<<<256, 256, 0, stream>>>(hB, hA, cb, emb, Wih, Whh, bih, bhh,
                                    slot, hist, -1, 0);
    for (int s = 0; s < 63; s++) {
        const float* hc = (s & 1) ? hB : hA;
        float* hn       = (s & 1) ? hA : hB;
        k_logit<<<500, 256, 0, stream>>>(hc, Whv, bhv, gu, s, slot);
        k_lstm<<<256, 256, 0, stream>>>(hc, hn, cb, emb, Wih, Whh, bih, bhh,
                                        slot, hist, s, (s == 62) ? 1 : 0);
    }
    k_out<<<1, 64, 0, stream>>>(hist, out);
    k_scatter<<<2048, 256, 0, stream>>>(out);
}

// Round 4
// 13814.128 us; speedup vs baseline: 1.1496x; 1.1496x over previous
//
#include <hip/hip_runtime.h>
#include <cstdint>
#include <cstddef>

#define NB 32
#define NT 64
#define NV 32000
#define NE 512
#define NH 1024
#define BOS_ID 1
#define EOS_ID 3

__device__ __forceinline__ unsigned mono_f32(float f) {
    unsigned u = __float_as_uint(f);
    return (u & 0x80000000u) ? ~u : (u | 0x80000000u);
}

// h0 = img @ Wp^T + bp ; c = 0
__global__ __launch_bounds__(256) void k_init(const float* __restrict__ img,
                                              const float* __restrict__ Wp,
                                              const float* __restrict__ bp,
                                              float* __restrict__ h0,
                                              float* __restrict__ c) {
    int g = blockIdx.x * 256 + threadIdx.x;   // 32768 outputs, one per thread
    int j = g >> 5, b = g & 31;
    const float* ir = img + (size_t)b * NH;   // D == 1024
    const float* wr = Wp + (size_t)j * NH;
    float s = bp[j];
    for (int k = 0; k < NH; k++) s = fmaf(ir[k], wr[k], s);
    h0[b * NH + j] = s;
    c[b * NH + j]  = 0.0f;
}

// logits + gumbel + argmax partial via device atomicMax.
// v5: coalesced-W-through-LDS GEMV. 500 blocks x 512 threads (8 waves).
//   lane l <-> v = blk*64 + l ; wave w <-> b in [4w, 4w+4).
//   W chunk [64 v][64 k] staged coalesced (lanes along k) into 16 KB LDS with
//   XOR col-quad swizzle q' = q ^ (v&7): store AND read both land at exactly
//   8 accesses/bank = ds b128 floor (verified by hand), zero excess conflict.
//   Lane reads its own W row from LDS (1 b128 per 16 FMAs); h is wave-uniform
//   (1-line float4 loads), double-buffered one 4k-sub ahead.
//   k-summation strictly ascending 0..1023 == round-0 passing order.
//   T14 reg-prefetch staging (global->regs early, regs->LDS after barrier).
__global__ __launch_bounds__(512) void k_logit(const float* __restrict__ h,
                                               const float* __restrict__ Whv,
                                               const float* __restrict__ bhv,
                                               const float* __restrict__ gu,
                                               int s,
                                               unsigned long long* __restrict__ slot) {
    __shared__ __align__(16) float Wlds[64][64];   // 16 KB, swizzled col-quads
    const int tid = threadIdx.x;
    const int l   = tid & 63;          // lane = v offset within block
    const int w   = tid >> 6;          // wave 0..7 -> b-group [4w, 4w+4)
    const int v   = blockIdx.x * 64 + l;
    const int lm  = l & 7;             // read-side swizzle key

    // staging map: thread covers row vv = tid>>3, k-octet kq2 = tid&7
    const int vv  = tid >> 3;          // 0..63
    const int kq2 = tid & 7;           // 0..7 -> k = 8*kq2 .. +7
    const float* __restrict__ wsrc =
        Whv + (size_t)(blockIdx.x * 64 + vv) * NH + kq2 * 8;
    const int q0 = (2 * kq2 + 0) ^ (vv & 7);   // store col-quads (0..15)
    const int q1 = (2 * kq2 + 1) ^ (vv & 7);

    const float* __restrict__ h0p = h + (w * 4 + 0) * NH;
    const float* __restrict__ h1p = h + (w * 4 + 1) * NH;
    const float* __restrict__ h2p = h + (w * 4 + 2) * NH;
    const float* __restrict__ h3p = h + (w * 4 + 3) * NH;

    float acc[4];
#pragma unroll
    for (int bi = 0; bi < 4; bi++) acc[bi] = 0.f;

    float4 st0, st1;
    st0 = *(const float4*)(wsrc + 0);
    st1 = *(const float4*)(wsrc + 4);

    for (int c = 0; c < 16; c++) {
        __syncthreads();                       // previous chunk's compute done
        *(float4*)&Wlds[vv][q0 * 4] = st0;     // regs -> LDS (waits vmcnt)
        *(float4*)&Wlds[vv][q1 * 4] = st1;
        if (c < 15) {                          // issue next chunk's loads early
            st0 = *(const float4*)(wsrc + (c + 1) * 64);
            st1 = *(const float4*)(wsrc + (c + 1) * 64 + 4);
        }
        __syncthreads();                       // LDS tile ready

        const int kc = c * 64;
        float4 hc0 = *(const float4*)&h0p[kc];
        float4 hc1 = *(const float4*)&h1p[kc];
        float4 hc2 = *(const float4*)&h2p[kc];
        float4 hc3 = *(const float4*)&h3p[kc];
#pragma unroll
        for (int t = 0; t < 16; t++) {
            float4 hn0, hn1, hn2, hn3;
            if (t < 15) {
                const int kn = kc + 4 * (t + 1);
                hn0 = *(const float4*)&h0p[kn];
                hn1 = *(const float4*)&h1p[kn];
                hn2 = *(const float4*)&h2p[kn];
                hn3 = *(const float4*)&h3p[kn];
            }
            const float4 w4 = *(const float4*)&Wlds[l][4 * (t ^ lm)];
            acc[0] = fmaf(hc0.x, w4.x, acc[0]); acc[0] = fmaf(hc0.y, w4.y, acc[0]);
            acc[0] = fmaf(hc0.z, w4.z, acc[0]); acc[0] = fmaf(hc0.w, w4.w, acc[0]);
            acc[1] = fmaf(hc1.x, w4.x, acc[1]); acc[1] = fmaf(hc1.y, w4.y, acc[1]);
            acc[1] = fmaf(hc1.z, w4.z, acc[1]); acc[1] = fmaf(hc1.w, w4.w, acc[1]);
            acc[2] = fmaf(hc2.x, w4.x, acc[2]); acc[2] = fmaf(hc2.y, w4.y, acc[2]);
            acc[2] = fmaf(hc2.z, w4.z, acc[2]); acc[2] = fmaf(hc2.w, w4.w, acc[2]);
            acc[3] = fmaf(hc3.x, w4.x, acc[3]); acc[3] = fmaf(hc3.y, w4.y, acc[3]);
            acc[3] = fmaf(hc3.z, w4.z, acc[3]); acc[3] = fmaf(hc3.w, w4.w, acc[3]);
            if (t < 15) { hc0 = hn0; hc1 = hn1; hc2 = hn2; hc3 = hn3; }
        }
    }

    // epilogue: lane owns (v, 4 b's) with FULL k-sums -- no cross-anything reduce.
    const float bv = bhv[v];
    const size_t gubase = (size_t)s * NB * NV;
#pragma unroll
    for (int bi = 0; bi < 4; bi++) {
        const int b = w * 4 + bi;
        float u  = gu[gubase + (size_t)b * NV + v];
        float g  = -logf(-logf(u + 1e-10f) + 1e-10f);
        float sc = acc[bi] + bv + g;          // TAU == 1.0
        unsigned long long key =
            ((unsigned long long)mono_f32(sc) << 32) | (unsigned)(~(unsigned)v);
#pragma unroll
        for (int m = 1; m < 64; m <<= 1) {
            unsigned long long o =
                (unsigned long long)__shfl_xor((long long)key, m, 64);
            if (o > key) key = o;
        }
        if (l == 0) atomicMax(&slot[(s & 1) * 32 + b], key);
    }
}

// argmax-finalize (read slots) + LSTM cell slice (4 h-outputs per block)
// v2: T14 async-stage split -- issue next chunk's global loads into regs
// before computing the current chunk; write regs->LDS after the barrier.
__global__ __launch_bounds__(256) void k_lstm(const float* __restrict__ h,
                                              float* __restrict__ hn,
                                              float* __restrict__ cbuf,
                                              const float* __restrict__ emb,
                                              const float* __restrict__ Wih,
                                              const float* __restrict__ Whh,
                                              const float* __restrict__ bih,
                                              const float* __restrict__ bhh,
                                              unsigned long long* __restrict__ slot,
                                              int* __restrict__ hist,
                                              int s, int skip) {
    __shared__ float Wt[512][20];   // [k][slot], stride 20: aligned f4, conflict-free reads
    __shared__ float xh[32][517];   // [b][k], stride 517: 2-way max on reads
    __shared__ int labels[32];
    const int tid = threadIdx.x, blk = blockIdx.x;
    const int b8 = tid >> 3, ks = tid & 7;

    if (s < 0) {
        if (tid < 32) labels[tid] = BOS_ID;
    } else {
        if (tid < 32) labels[tid] = (int)(~(unsigned)slot[(s & 1) * 32 + tid]);
    }
    if (tid >= 32 && tid < 64)
        slot[((s + 1) & 1) * 32 + (tid - 32)] = 0ull;   // pre-zero next parity
    if (s >= 0 && blk == 0 && tid < 32) hist[s * 32 + tid] = labels[tid];
    if (skip) return;

    const int j0 = blk * 4;
    float acc[16];
#pragma unroll
    for (int r = 0; r < 16; r++) acc[r] = 0.f;

    float wreg[32];
    float xreg[64];
    auto issue = [&](int chunk) {
#pragma unroll
        for (int i = 0; i < 32; i++) {     // 16 gate rows x 512 k -> regs
            int idx = i * 256 + tid;
            int slot_i = idx >> 9, k = idx & 511;
            int gate = slot_i >> 2, jj = slot_i & 3;
            int row = gate * NH + j0 + jj;
            wreg[i] = (chunk == 0) ? Wih[(size_t)row * NE + k]
                                   : Whh[(size_t)row * NH + (chunk - 1) * 512 + k];
        }
#pragma unroll
        for (int i = 0; i < 64; i++) {     // x / h chunk -> regs
            int idx = i * 256 + tid;
            int b = idx >> 9, k = idx & 511;
            xreg[i] = (chunk == 0) ? emb[(size_t)labels[b] * NE + k]
                                   : h[b * NH + (chunk - 1) * 512 + k];
        }
    };

    __syncthreads();                       // labels visible to all threads
    issue(0);
    for (int chunk = 0; chunk < 3; chunk++) {
        __syncthreads();                   // prior compute on LDS done
#pragma unroll
        for (int i = 0; i < 32; i++) {
            int idx = i * 256 + tid;
            Wt[idx & 511][idx >> 9] = wreg[i];
        }
#pragma unroll
        for (int i = 0; i < 64; i++) {
            int idx = i * 256 + tid;
            xh[idx >> 9][idx & 511] = xreg[i];
        }
        if (chunk < 2) issue(chunk + 1);   // overlap next-chunk loads w/ compute
        __syncthreads();
#pragma unroll 4
        for (int i = 0; i < 64; i++) {
            int k = ks + 8 * i;
            float xv = xh[b8][k];
            const float4 w0 = *(const float4*)&Wt[k][0];
            const float4 w1 = *(const float4*)&Wt[k][4];
            const float4 w2 = *(const float4*)&Wt[k][8];
            const float4 w3 = *(const float4*)&Wt[k][12];
            acc[0]  = fmaf(xv, w0.x, acc[0]);  acc[1]  = fmaf(xv, w0.y, acc[1]);
            acc[2]  = fmaf(xv, w0.z, acc[2]);  acc[3]  = fmaf(xv, w0.w, acc[3]);
            acc[4]  = fmaf(xv, w1.x, acc[4]);  acc[5]  = fmaf(xv, w1.y, acc[5]);
            acc[6]  = fmaf(xv, w1.z, acc[6]);  acc[7]  = fmaf(xv, w1.w, acc[7]);
            acc[8]  = fmaf(xv, w2.x, acc[8]);  acc[9]  = fmaf(xv, w2.y, acc[9]);
            acc[10] = fmaf(xv, w2.z, acc[10]); acc[11] = fmaf(xv, w2.w, acc[11]);
            acc[12] = fmaf(xv, w3.x, acc[12]); acc[13] = fmaf(xv, w3.y, acc[13]);
            acc[14] = fmaf(xv, w3.z, acc[14]); acc[15] = fmaf(xv, w3.w, acc[15]);
        }
    }
#pragma unroll
    for (int m = 1; m < 8; m <<= 1)
#pragma unroll
        for (int r = 0; r < 16; r++) acc[r] += __shfl_xor(acc[r], m, 64);

    if (ks == 0) {
        int b = b8;
#pragma unroll
        for (int jj = 0; jj < 4; jj++) {
            int j = j0 + jj;
            float gi = acc[0 + jj]  + bih[j]          + bhh[j];
            float gf = acc[4 + jj]  + bih[NH + j]     + bhh[NH + j];
            float gg = acc[8 + jj]  + bih[2 * NH + j] + bhh[2 * NH + j];
            float go = acc[12 + jj] + bih[3 * NH + j] + bhh[3 * NH + j];
            float si = 1.f / (1.f + expf(-gi));
            float sf = 1.f / (1.f + expf(-gf));
            float so = 1.f / (1.f + expf(-go));
            float cn = sf * cbuf[b * NH + j] + si * tanhf(gg);
            float hv = so * tanhf(cn);
            cbuf[b * NH + j] = cn;
            hn[b * NH + j]   = hv;
        }
    }
}

// ids / lengths from label history
__global__ __launch_bounds__(64) void k_out(const int* __restrict__ hist,
                                            float* __restrict__ out) {
    int b = threadIdx.x;
    if (b >= 32) return;
    int te = 63;   // first EOS index (t=63 forced EOS)
    for (int t = 0; t < 63; t++)
        if (hist[t * 32 + b] == EOS_ID) { te = t; break; }
    for (int t = 0; t < 64; t++) {
        int lab = (t < 63) ? hist[t * 32 + b] : EOS_ID;
        int id = (t < te) ? lab : 0;           // pad_g true strictly before first EOS
        out[b * 64 + t] = (float)id;
    }
    out[2048 + (size_t)NB * NT * NV + b] = (float)(te + 1);
}

// zero logits region + scatter one-hot (message_logits == one_hot(message_ids))
__global__ __launch_bounds__(256) void k_scatter(float* __restrict__ out) {
    const int bt = blockIdx.x;                 // b*64 + t
    float* row = out + 2048 + (size_t)bt * NV;
    const int id = (int)out[bt];               // ids already written by k_out
    float4 z = make_float4(0.f, 0.f, 0.f, 0.f);
    for (int i = threadIdx.x; i < NV / 4; i += 256) ((float4*)row)[i] = z;
    __syncthreads();
    if (threadIdx.x == 0) row[id] = 1.0f;
}

extern "C" void kernel_launch(void* const* d_in, const int* in_sizes, int n_in,
                              void* d_out, int out_size, void* d_ws, size_t ws_size,
                              hipStream_t stream) {
    const float* img = (const float*)d_in[0];
    const float* gu  = (const float*)d_in[1];
    const float* Wp  = (const float*)d_in[2];
    const float* bp  = (const float*)d_in[3];
    const float* emb = (const float*)d_in[4];
    const float* Wih = (const float*)d_in[5];
    const float* Whh = (const float*)d_in[6];
    const float* bih = (const float*)d_in[7];
    const float* bhh = (const float*)d_in[8];
    const float* Whv = (const float*)d_in[9];
    const float* bhv = (const float*)d_in[10];
    float* out = (float*)d_out;

    // scratch lives inside the logits region of d_out (fully overwritten by k_scatter)
    float* scratch = out + 2048;
    float* hA = scratch;                 // 32768
    float* hB = scratch + 32768;         // 32768
    float* cb = scratch + 65536;         // 32768
    unsigned long long* slot = (unsigned long long*)(scratch + 98304); // 64 u64 (2 parities)
    int* hist = (int*)(scratch + 98304 + 128);                         // 63*32 ints

    k_init<<<128, 256, 0, stream>>>(img, Wp, bp, hB, cb);
    // initial LSTM cell with x0 = emb[BOS], h = h0, c = 0 -> writes hA; zeroes slot parity 0
    k_lstm<<<256, 256, 0, stream>>>(hB, hA, cb, emb, Wih, Whh, bih, bhh,
                                    slot, hist, -1, 0);
    for (int s = 0; s < 63; s++) {
        const float* hc = (s & 1) ? hB : hA;
        float* hn       = (s & 1) ? hA : hB;
        k_logit<<<500, 512, 0, stream>>>(hc, Whv, bhv, gu, s, slot);
        k_lstm<<<256, 256, 0, stream>>>(hc, hn, cb, emb, Wih, Whh, bih, bhh,
                                        slot, hist, s, (s == 62) ? 1 : 0);
    }
    k_out<<<1, 64, 0, stream>>>(hist, out);
    k_scatter<<<2048, 256, 0, stream>>>(out);
}